// Round 1
// baseline (1255.650 us; speedup 1.0000x reference)
//
#include <hip/hip_runtime.h>
#include <math.h>

#define D_DIM 1024
#define A_DIM 256
#define E_NUM 16
#define M_TOT 32768   // B*S = 32*1024

__device__ __forceinline__ float gelu_exact(float x) {
    return 0.5f * x * (1.0f + erff(x * 0.70710678118654752f));
}

// ---------------------------------------------------------------------------
// K1: H[m,a] = gelu( sum_d X[m,d] * Wd[a,d] + bd[a] )
// M=32768, N=256, K=1024.  64x64 tile, 256 threads, 4x4 micro-tile, K-step 16.
// ---------------------------------------------------------------------------
__global__ __launch_bounds__(256) void k_down_gelu(
    const float* __restrict__ X, const float* __restrict__ Wd,
    const float* __restrict__ bd, float* __restrict__ H)
{
    // stride 20 floats = 80B (multiple of 16B -> float4-aligned rows)
    __shared__ float As[64][20];
    __shared__ float Bs[64][20];
    const int tid = threadIdx.x;
    const int m0 = blockIdx.y * 64;
    const int n0 = blockIdx.x * 64;
    const int lr = tid >> 2;           // 0..63
    const int lc = (tid & 3) << 2;     // 0,4,8,12
    const int tx = tid & 15, ty = tid >> 4;

    float acc[4][4];
    #pragma unroll
    for (int i = 0; i < 4; i++)
        #pragma unroll
        for (int j = 0; j < 4; j++) acc[i][j] = 0.f;

    for (int kt = 0; kt < D_DIM; kt += 16) {
        float4 av = *(const float4*)(X  + (size_t)(m0 + lr) * D_DIM + kt + lc);
        float4 bv = *(const float4*)(Wd + (size_t)(n0 + lr) * D_DIM + kt + lc);
        *(float4*)&As[lr][lc] = av;
        *(float4*)&Bs[lr][lc] = bv;
        __syncthreads();
        #pragma unroll
        for (int k = 0; k < 16; k += 4) {
            float4 a[4], b[4];
            #pragma unroll
            for (int i = 0; i < 4; i++) a[i] = *(const float4*)&As[ty * 4 + i][k];
            #pragma unroll
            for (int j = 0; j < 4; j++) b[j] = *(const float4*)&Bs[tx * 4 + j][k];
            #pragma unroll
            for (int i = 0; i < 4; i++)
                #pragma unroll
                for (int j = 0; j < 4; j++)
                    acc[i][j] += a[i].x * b[j].x + a[i].y * b[j].y
                               + a[i].z * b[j].z + a[i].w * b[j].w;
        }
        __syncthreads();
    }

    float4 bb = *(const float4*)(bd + n0 + tx * 4);
    #pragma unroll
    for (int i = 0; i < 4; i++) {
        float4 o;
        o.x = gelu_exact(acc[i][0] + bb.x);
        o.y = gelu_exact(acc[i][1] + bb.y);
        o.z = gelu_exact(acc[i][2] + bb.z);
        o.w = gelu_exact(acc[i][3] + bb.w);
        *(float4*)(H + (size_t)(m0 + ty * 4 + i) * A_DIM + n0 + tx * 4) = o;
    }
}

// ---------------------------------------------------------------------------
// K2: fused expert-GEMM + domain emb + up-proj + bias + residual + LayerNorm.
// One block = 16 rows (all within one sample), 256 threads.
// ---------------------------------------------------------------------------
__global__ __launch_bounds__(256) void k_fused(
    const float* __restrict__ H, const float* __restrict__ X,
    const int* __restrict__ domain_id,
    const float* __restrict__ upW, const float* __restrict__ upb,
    const float* __restrict__ eW, const float* __restrict__ eb,
    const float* __restrict__ emb,
    const float* __restrict__ gamma, const float* __restrict__ beta,
    float* __restrict__ out)
{
    __shared__ float h1s[16 * 256];
    __shared__ float h2s[16 * 256];
    __shared__ float mu_s[16], rs_s[16];
    const int tid = threadIdx.x;
    const int row0 = blockIdx.x * 16;
    const int bidx = row0 >> 10;                // sample index (1024 rows/sample)
    const int id = domain_id[bidx];
    const bool valid = (id >= 0) && (id < E_NUM);
    const int idc = id < 0 ? 0 : (id > E_NUM - 1 ? E_NUM - 1 : id);

    // stage h1 rows: 16x256 floats, coalesced float4
    float4* h1s4 = (float4*)h1s;
    const float4* hg = (const float4*)(H + (size_t)row0 * A_DIM);
    #pragma unroll
    for (int p = 0; p < 4; p++) h1s4[tid + p * 256] = hg[tid + p * 256];
    __syncthreads();

    // expert: thread owns output column c = tid for all 16 rows
    {
        const int c = tid;
        float res[16];
        if (valid) {
            float acc[16];
            #pragma unroll
            for (int r = 0; r < 16; r++) acc[r] = 0.f;
            const float4* wr = (const float4*)(eW + ((size_t)idc * A_DIM + c) * A_DIM);
            for (int k4 = 0; k4 < 64; k4++) {
                float4 w = wr[k4];
                #pragma unroll
                for (int r = 0; r < 16; r++) {
                    float4 h = h1s4[r * 64 + k4];   // uniform addr -> broadcast
                    acc[r] += h.x * w.x + h.y * w.y + h.z * w.z + h.w * w.w;
                }
            }
            float bev = eb[idc * A_DIM + c];
            #pragma unroll
            for (int r = 0; r < 16; r++) res[r] = acc[r] + bev;
        } else {
            #pragma unroll
            for (int r = 0; r < 16; r++) res[r] = h1s[r * A_DIM + c];
        }
        float ev = emb[idc * A_DIM + c];
        #pragma unroll
        for (int r = 0; r < 16; r++) h2s[r * A_DIM + c] = res[r] + ev;
    }
    __syncthreads();

    // up-proj: thread owns cols d = tid + 256*j, j=0..3, for all 16 rows
    float xv[4][16];
    float s1p[16], s2p[16];
    #pragma unroll
    for (int r = 0; r < 16; r++) { s1p[r] = 0.f; s2p[r] = 0.f; }
    const float4* h2s4 = (const float4*)h2s;
    #pragma unroll
    for (int j = 0; j < 4; j++) {
        const int d = tid + j * 256;
        const float4* wr = (const float4*)(upW + (size_t)d * A_DIM);
        float acc[16];
        #pragma unroll
        for (int r = 0; r < 16; r++) acc[r] = 0.f;
        for (int k4 = 0; k4 < 64; k4++) {
            float4 w = wr[k4];
            #pragma unroll
            for (int r = 0; r < 16; r++) {
                float4 h = h2s4[r * 64 + k4];   // uniform addr -> broadcast
                acc[r] += h.x * w.x + h.y * w.y + h.z * w.z + h.w * w.w;
            }
        }
        float ubv = upb[d];
        #pragma unroll
        for (int r = 0; r < 16; r++) {
            float x = acc[r] + ubv + X[(size_t)(row0 + r) * D_DIM + d];
            xv[j][r] = x;
            s1p[r] += x;
            s2p[r] += x * x;
        }
    }

    // block LN reduction: alias h1s/h2s as [16][256] partial-sum buffers
    __syncthreads();               // all h2s reads done before aliasing
    float* s1buf = h1s;
    float* s2buf = h2s;
    #pragma unroll
    for (int r = 0; r < 16; r++) {
        s1buf[r * 256 + tid] = s1p[r];
        s2buf[r * 256 + tid] = s2p[r];
    }
    __syncthreads();
    for (int s = 128; s > 0; s >>= 1) {
        if (tid < s) {
            #pragma unroll
            for (int r = 0; r < 16; r++) {
                s1buf[r * 256 + tid] += s1buf[r * 256 + tid + s];
                s2buf[r * 256 + tid] += s2buf[r * 256 + tid + s];
            }
        }
        __syncthreads();
    }
    if (tid < 16) {
        float m = s1buf[tid * 256] * (1.0f / 1024.0f);
        float v = s2buf[tid * 256] * (1.0f / 1024.0f) - m * m;
        mu_s[tid] = m;
        rs_s[tid] = rsqrtf(v + 1e-5f);
    }
    __syncthreads();

    #pragma unroll
    for (int j = 0; j < 4; j++) {
        const int d = tid + j * 256;
        float g = gamma[d], be2 = beta[d];
        #pragma unroll
        for (int r = 0; r < 16; r++) {
            out[(size_t)(row0 + r) * D_DIM + d] =
                (xv[j][r] - mu_s[r]) * rs_s[r] * g + be2;
        }
    }
}

extern "C" void kernel_launch(void* const* d_in, const int* in_sizes, int n_in,
                              void* d_out, int out_size, void* d_ws, size_t ws_size,
                              hipStream_t stream) {
    const float* hs   = (const float*)d_in[0];   // [32,1024,1024]
    const int*   did  = (const int*)d_in[1];     // [32]
    const float* dW   = (const float*)d_in[2];   // [256,1024]
    const float* db   = (const float*)d_in[3];   // [256]
    const float* uW   = (const float*)d_in[4];   // [1024,256]
    const float* ub   = (const float*)d_in[5];   // [1024]
    const float* eW   = (const float*)d_in[6];   // [16,256,256]
    const float* ebv  = (const float*)d_in[7];   // [16,256]
    const float* emb  = (const float*)d_in[8];   // [16,256]
    const float* gam  = (const float*)d_in[9];   // [1024]
    const float* bet  = (const float*)d_in[10];  // [1024]
    float* out = (float*)d_out;
    float* h1  = (float*)d_ws;                   // [32768,256] fp32 = 134 MB

    dim3 g1(A_DIM / 64, M_TOT / 64);             // (4, 512)
    k_down_gelu<<<g1, dim3(256), 0, stream>>>(hs, dW, db, h1);

    dim3 g2(M_TOT / 16);                         // 2048
    k_fused<<<g2, dim3(256), 0, stream>>>(h1, hs, did, uW, ub, eW, ebv, emb,
                                          gam, bet, out);
}

// Round 2
// 437.781 us; speedup vs baseline: 2.8682x; 2.8682x over previous
//
#include <hip/hip_runtime.h>
#include <hip/hip_bf16.h>
#include <math.h>

#define D_DIM 1024
#define A_DIM 256
#define E_NUM 16
#define M_TOT 32768   // B*S

typedef __attribute__((ext_vector_type(8))) short short8;   // 8 bf16 (4 VGPRs)
typedef __attribute__((ext_vector_type(4))) float f32x4;    // MFMA acc

__device__ __forceinline__ short f2bs(float x) {
    __hip_bfloat16 h = __float2bfloat16(x);   // RNE
    return __builtin_bit_cast(short, h);
}
__device__ __forceinline__ float bs2f(short s) {
    __hip_bfloat16 h = __builtin_bit_cast(__hip_bfloat16, s);
    return __bfloat162float(h);
}
__device__ __forceinline__ float gelu_exact(float x) {
    return 0.5f * x * (1.0f + erff(x * 0.70710678118654752f));
}
// async global->LDS, 16B per lane; LDS dest must be wave-uniform base + lane*16
__device__ __forceinline__ void gload_lds16(const void* g, void* l) {
    __builtin_amdgcn_global_load_lds(
        (const __attribute__((address_space(1))) void*)g,
        (__attribute__((address_space(3))) void*)l, 16, 0, 0);
}

// ---------------------------------------------------------------------------
// cast weights fp32 -> bf16 into workspace
// ---------------------------------------------------------------------------
__global__ __launch_bounds__(256) void k_cast_w(
    const float* __restrict__ Wd, const float* __restrict__ Wu,
    const float* __restrict__ eW,
    short* __restrict__ WdB, short* __restrict__ WuB, short* __restrict__ eWB)
{
    int i = blockIdx.x * 256 + threadIdx.x;
    if (i < 262144) WdB[i] = f2bs(Wd[i]);
    if (i < 262144) WuB[i] = f2bs(Wu[i]);
    if (i < 1048576) eWB[i] = f2bs(eW[i]);
}

// ---------------------------------------------------------------------------
// down proj: H1[m,a] = gelu(X[m,:]*WdB[a,:] + bd[a]),  M=32768,N=256,K=1024
// 128x128 tile, 4 waves in 2x2, 4x4 frags of 16x16x32, BK=64.
// A (X) is fp32: staged via VGPR cvt; B via global_load_lds.
// ---------------------------------------------------------------------------
__global__ __launch_bounds__(256, 2) void k_down(
    const float* __restrict__ X, const short* __restrict__ WdB,
    const float* __restrict__ bd, short* __restrict__ H1)
{
    __shared__ short As[128][64];
    __shared__ short Bs[128][64];
    const int tid  = threadIdx.x;
    const int lane = tid & 63;
    const int w    = tid >> 6;
    const int wm   = w & 1, wn = w >> 1;
    const int quad = lane >> 4, cid = lane & 15;
    const int m0 = blockIdx.y * 128, n0 = blockIdx.x * 128;

    const int ar  = tid >> 1;          // A staging: row
    const int ac0 = (tid & 1) * 32;    // A staging: col base (32 floats)

    f32x4 acc[4][4];
    #pragma unroll
    for (int i = 0; i < 4; i++)
        #pragma unroll
        for (int j = 0; j < 4; j++) acc[i][j] = (f32x4)(0.f);

    for (int kt = 0; kt < D_DIM; kt += 64) {
        // A: 32 fp32 -> 32 bf16 -> LDS (4 x 16B)
        const float4* src = (const float4*)(X + (size_t)(m0 + ar) * D_DIM + kt + ac0);
        #pragma unroll
        for (int i = 0; i < 4; i++) {
            float4 u = src[2 * i], v = src[2 * i + 1];
            short8 pk;
            pk[0] = f2bs(u.x); pk[1] = f2bs(u.y); pk[2] = f2bs(u.z); pk[3] = f2bs(u.w);
            pk[4] = f2bs(v.x); pk[5] = f2bs(v.y); pk[6] = f2bs(v.z); pk[7] = f2bs(v.w);
            *(short8*)&As[ar][ac0 + i * 8] = pk;
        }
        // B: 128x64 bf16 = 16KB via global_load_lds (4 chunks/thread)
        #pragma unroll
        for (int p = 0; p < 4; p++) {
            int j = tid + p * 256;
            int r = j >> 3, c = (j & 7) * 8;
            gload_lds16(WdB + (size_t)(n0 + r) * D_DIM + kt + c, &Bs[r][c]);
        }
        __syncthreads();
        #pragma unroll
        for (int kk = 0; kk < 2; kk++) {
            short8 a[4], b[4];
            #pragma unroll
            for (int i = 0; i < 4; i++)
                a[i] = *(const short8*)&As[wm * 64 + i * 16 + cid][kk * 32 + quad * 8];
            #pragma unroll
            for (int j = 0; j < 4; j++)
                b[j] = *(const short8*)&Bs[wn * 64 + j * 16 + cid][kk * 32 + quad * 8];
            #pragma unroll
            for (int i = 0; i < 4; i++)
                #pragma unroll
                for (int j = 0; j < 4; j++)
                    acc[i][j] = __builtin_amdgcn_mfma_f32_16x16x32_bf16(
                        a[i], b[j], acc[i][j], 0, 0, 0);
        }
        __syncthreads();
    }
    // epilogue: bias + exact GELU -> bf16
    #pragma unroll
    for (int j = 0; j < 4; j++) {
        int col = n0 + wn * 64 + j * 16 + cid;
        float bdv = bd[col];
        #pragma unroll
        for (int i = 0; i < 4; i++)
            #pragma unroll
            for (int r = 0; r < 4; r++) {
                int row = m0 + wm * 64 + i * 16 + quad * 4 + r;
                H1[(size_t)row * A_DIM + col] = f2bs(gelu_exact(acc[i][j][r] + bdv));
            }
    }
}

// ---------------------------------------------------------------------------
// expert: H2[m,o] = (valid ? H1[m,:]*eW[idc][o,:] + eb[idc,o] : H1[m,o]) + emb[idc,o]
// M-tile of 128 rows stays inside one sample (S=1024). M=32768,N=256,K=256.
// ---------------------------------------------------------------------------
__global__ __launch_bounds__(256, 2) void k_expert(
    const short* __restrict__ H1, const short* __restrict__ eWB,
    const float* __restrict__ eb, const float* __restrict__ emb,
    const int* __restrict__ domain_id, short* __restrict__ H2)
{
    __shared__ short As[128][64];
    __shared__ short Bs[128][64];
    const int tid  = threadIdx.x;
    const int lane = tid & 63;
    const int w    = tid >> 6;
    const int wm   = w & 1, wn = w >> 1;
    const int quad = lane >> 4, cid = lane & 15;
    const int m0 = blockIdx.y * 128, n0 = blockIdx.x * 128;

    const int samp = m0 >> 10;
    const int id = domain_id[samp];
    const bool valid = (id >= 0) && (id < E_NUM);
    const int idc = id < 0 ? 0 : (id > E_NUM - 1 ? E_NUM - 1 : id);
    const short* Bsrc = eWB + (size_t)idc * A_DIM * A_DIM;

    f32x4 acc[4][4];
    #pragma unroll
    for (int i = 0; i < 4; i++)
        #pragma unroll
        for (int j = 0; j < 4; j++) acc[i][j] = (f32x4)(0.f);

    for (int kt = 0; kt < A_DIM; kt += 64) {
        #pragma unroll
        for (int p = 0; p < 4; p++) {
            int j = tid + p * 256;
            int r = j >> 3, c = (j & 7) * 8;
            gload_lds16(H1 + (size_t)(m0 + r) * A_DIM + kt + c, &As[r][c]);
            gload_lds16(Bsrc + (size_t)(n0 + r) * A_DIM + kt + c, &Bs[r][c]);
        }
        __syncthreads();
        #pragma unroll
        for (int kk = 0; kk < 2; kk++) {
            short8 a[4], b[4];
            #pragma unroll
            for (int i = 0; i < 4; i++)
                a[i] = *(const short8*)&As[wm * 64 + i * 16 + cid][kk * 32 + quad * 8];
            #pragma unroll
            for (int j = 0; j < 4; j++)
                b[j] = *(const short8*)&Bs[wn * 64 + j * 16 + cid][kk * 32 + quad * 8];
            #pragma unroll
            for (int i = 0; i < 4; i++)
                #pragma unroll
                for (int j = 0; j < 4; j++)
                    acc[i][j] = __builtin_amdgcn_mfma_f32_16x16x32_bf16(
                        a[i], b[j], acc[i][j], 0, 0, 0);
        }
        __syncthreads();
    }
    #pragma unroll
    for (int j = 0; j < 4; j++) {
        int col = n0 + wn * 64 + j * 16 + cid;
        float ebv = eb[idc * A_DIM + col];
        float ev  = emb[idc * A_DIM + col];
        #pragma unroll
        for (int i = 0; i < 4; i++)
            #pragma unroll
            for (int r = 0; r < 4; r++) {
                int row = m0 + wm * 64 + i * 16 + quad * 4 + r;
                float base;
                if (valid) base = acc[i][j][r] + ebv;
                else       base = bs2f(H1[(size_t)row * A_DIM + col]);
                H2[(size_t)row * A_DIM + col] = f2bs(base + ev);
            }
    }
}

// ---------------------------------------------------------------------------
// up proj + bias + residual + LayerNorm, fused.
// Block = 32 full rows x 1024 cols (LN rows complete in-block). 4 waves, each
// wave: 256 cols -> 2x16 frags. K=256, BK=64. B frags straight from L2
// (up_W bf16 = 512KB, resident). x kept in acc registers through LN.
// ---------------------------------------------------------------------------
__global__ __launch_bounds__(256, 2) void k_up_ln(
    const short* __restrict__ H2, const short* __restrict__ WuB,
    const float* __restrict__ ub, const float* __restrict__ X,
    const float* __restrict__ gamma, const float* __restrict__ beta,
    float* __restrict__ out)
{
    __shared__ short As[32][64];
    __shared__ float redS[4][32], red2[4][32];
    __shared__ float muS[32], rsS[32];
    const int tid  = threadIdx.x;
    const int lane = tid & 63;
    const int w    = tid >> 6;
    const int quad = lane >> 4, cid = lane & 15;
    const int m0 = blockIdx.x * 32;
    const int nb = w * 256;

    f32x4 acc[2][16];
    #pragma unroll
    for (int mf = 0; mf < 2; mf++)
        #pragma unroll
        for (int j = 0; j < 16; j++) acc[mf][j] = (f32x4)(0.f);

    const short* bbase = WuB + (size_t)(nb + cid) * A_DIM + quad * 8;

    for (int kt = 0; kt < A_DIM; kt += 64) {
        {
            int r = tid >> 3, c = (tid & 7) * 8;   // 32x64 bf16 = 4KB, 1 chunk/thread
            gload_lds16(H2 + (size_t)(m0 + r) * A_DIM + kt + c, &As[r][c]);
        }
        __syncthreads();
        #pragma unroll
        for (int kk = 0; kk < 2; kk++) {
            short8 a0 = *(const short8*)&As[cid][kk * 32 + quad * 8];
            short8 a1 = *(const short8*)&As[16 + cid][kk * 32 + quad * 8];
            #pragma unroll
            for (int j = 0; j < 16; j++) {
                short8 b = *(const short8*)(bbase + (size_t)j * 16 * A_DIM + kt + kk * 32);
                acc[0][j] = __builtin_amdgcn_mfma_f32_16x16x32_bf16(a0, b, acc[0][j], 0, 0, 0);
                acc[1][j] = __builtin_amdgcn_mfma_f32_16x16x32_bf16(a1, b, acc[1][j], 0, 0, 0);
            }
        }
        __syncthreads();
    }

    // x = acc + up_b + residual; accumulate row sums
    float s1[2][4], s2[2][4];
    #pragma unroll
    for (int mf = 0; mf < 2; mf++)
        #pragma unroll
        for (int r = 0; r < 4; r++) { s1[mf][r] = 0.f; s2[mf][r] = 0.f; }
    #pragma unroll
    for (int j = 0; j < 16; j++) {
        int col = nb + j * 16 + cid;
        float ubv = ub[col];
        #pragma unroll
        for (int mf = 0; mf < 2; mf++)
            #pragma unroll
            for (int r = 0; r < 4; r++) {
                int row = m0 + mf * 16 + quad * 4 + r;
                float x = acc[mf][j][r] + ubv + X[(size_t)row * D_DIM + col];
                acc[mf][j][r] = x;
                s1[mf][r] += x;
                s2[mf][r] += x * x;
            }
    }
    // reduce over the 16 lanes sharing a row (xor 1,2,4,8)
    #pragma unroll
    for (int mf = 0; mf < 2; mf++)
        #pragma unroll
        for (int r = 0; r < 4; r++) {
            float a = s1[mf][r], b = s2[mf][r];
            #pragma unroll
            for (int off = 1; off < 16; off <<= 1) {
                a += __shfl_xor(a, off, 64);
                b += __shfl_xor(b, off, 64);
            }
            if (cid == 0) {
                int rl = mf * 16 + quad * 4 + r;
                redS[w][rl] = a;
                red2[w][rl] = b;
            }
        }
    __syncthreads();
    if (tid < 32) {
        float S = redS[0][tid] + redS[1][tid] + redS[2][tid] + redS[3][tid];
        float Q = red2[0][tid] + red2[1][tid] + red2[2][tid] + red2[3][tid];
        float mu = S * (1.0f / 1024.0f);
        float var = Q * (1.0f / 1024.0f) - mu * mu;
        muS[tid] = mu;
        rsS[tid] = rsqrtf(var + 1e-5f);
    }
    __syncthreads();
    #pragma unroll
    for (int j = 0; j < 16; j++) {
        int col = nb + j * 16 + cid;
        float g = gamma[col], be = beta[col];
        #pragma unroll
        for (int mf = 0; mf < 2; mf++)
            #pragma unroll
            for (int r = 0; r < 4; r++) {
                int rl = mf * 16 + quad * 4 + r;
                out[(size_t)(m0 + rl) * D_DIM + col] =
                    (acc[mf][j][r] - muS[rl]) * rsS[rl] * g + be;
            }
    }
}

extern "C" void kernel_launch(void* const* d_in, const int* in_sizes, int n_in,
                              void* d_out, int out_size, void* d_ws, size_t ws_size,
                              hipStream_t stream) {
    const float* hs  = (const float*)d_in[0];   // [32,1024,1024]
    const int*   did = (const int*)d_in[1];     // [32]
    const float* dW  = (const float*)d_in[2];   // [256,1024]
    const float* db  = (const float*)d_in[3];   // [256]
    const float* uW  = (const float*)d_in[4];   // [1024,256]
    const float* ub  = (const float*)d_in[5];   // [1024]
    const float* eW  = (const float*)d_in[6];   // [16,256,256]
    const float* ebv = (const float*)d_in[7];   // [16,256]
    const float* emb = (const float*)d_in[8];   // [16,256]
    const float* gam = (const float*)d_in[9];   // [1024]
    const float* bet = (const float*)d_in[10];  // [1024]
    float* out = (float*)d_out;

    char* ws = (char*)d_ws;
    short* WdB = (short*)(ws);                          // 512 KB
    short* WuB = (short*)(ws + (1u << 19));             // 512 KB
    short* eWB = (short*)(ws + (1u << 20));             // 2 MB
    short* H1  = (short*)(ws + (4u << 20));             // 16 MB
    short* H2  = (short*)(ws + (4u << 20) + (16u << 20)); // 16 MB  (total 36 MB)

    k_cast_w<<<4096, 256, 0, stream>>>(dW, uW, eW, WdB, WuB, eWB);
    k_down  <<<dim3(2, 256), 256, 0, stream>>>(hs, WdB, db, H1);
    k_expert<<<dim3(2, 256), 256, 0, stream>>>(H1, eWB, ebv, emb, did, H2);
    k_up_ln <<<1024, 256, 0, stream>>>(H2, WuB, ub, hs, gam, bet, out);
}

// Round 3
// 399.729 us; speedup vs baseline: 3.1413x; 1.0952x over previous
//
#include <hip/hip_runtime.h>
#include <hip/hip_bf16.h>
#include <math.h>

#define D_DIM 1024
#define A_DIM 256
#define E_NUM 16
#define M_TOT 32768   // B*S

typedef __attribute__((ext_vector_type(8))) short short8;   // 8 bf16 (4 VGPRs)
typedef __attribute__((ext_vector_type(4))) float f32x4;    // MFMA acc

__device__ __forceinline__ short f2bs(float x) {
    __hip_bfloat16 h = __float2bfloat16(x);   // RNE
    return __builtin_bit_cast(short, h);
}
__device__ __forceinline__ float bs2f(short s) {
    __hip_bfloat16 h = __builtin_bit_cast(__hip_bfloat16, s);
    return __bfloat162float(h);
}
__device__ __forceinline__ float gelu_exact(float x) {
    return 0.5f * x * (1.0f + erff(x * 0.70710678118654752f));
}
// async global->LDS, 16B per lane; LDS dest must be wave-uniform base + lane*16
__device__ __forceinline__ void gload_lds16(const void* g, void* l) {
    __builtin_amdgcn_global_load_lds(
        (const __attribute__((address_space(1))) void*)g,
        (__attribute__((address_space(3))) void*)l, 16, 0, 0);
}

// ---------------------------------------------------------------------------
// cast: X (33.5M fp32) -> bf16, plus the three weight tensors.
// One thread = 8 X elements (2 float4 loads, 1 short8 store).
// ---------------------------------------------------------------------------
__global__ __launch_bounds__(256) void k_cast(
    const float* __restrict__ X, const float* __restrict__ Wd,
    const float* __restrict__ Wu, const float* __restrict__ eW,
    short* __restrict__ XB, short* __restrict__ WdB,
    short* __restrict__ WuB, short* __restrict__ eWB)
{
    unsigned i = blockIdx.x * 256 + threadIdx.x;   // 4,194,304 threads
    const float4* xs = (const float4*)X;
    float4 u = xs[2 * (size_t)i], v = xs[2 * (size_t)i + 1];
    short8 pk;
    pk[0] = f2bs(u.x); pk[1] = f2bs(u.y); pk[2] = f2bs(u.z); pk[3] = f2bs(u.w);
    pk[4] = f2bs(v.x); pk[5] = f2bs(v.y); pk[6] = f2bs(v.z); pk[7] = f2bs(v.w);
    ((short8*)XB)[i] = pk;
    if (i < 1048576) eWB[i] = f2bs(eW[i]);
    if (i < 262144) { WdB[i] = f2bs(Wd[i]); WuB[i] = f2bs(Wu[i]); }
}

// ---------------------------------------------------------------------------
// down proj: H1[m,a] = gelu(XB[m,:]*WdB[a,:] + bd[a]),  M=32768,N=256,K=1024
// 128x128 tile, 4 waves 2x2, 4x4 frags of 16x16x32, BK=64, both sides DMA.
// ---------------------------------------------------------------------------
__global__ __launch_bounds__(256, 2) void k_down(
    const short* __restrict__ XB, const short* __restrict__ WdB,
    const float* __restrict__ bd, short* __restrict__ H1)
{
    __shared__ short As[128][64];
    __shared__ short Bs[128][64];
    const int tid  = threadIdx.x;
    const int lane = tid & 63;
    const int w    = tid >> 6;
    const int wm   = w & 1, wn = w >> 1;
    const int quad = lane >> 4, cid = lane & 15;
    const int m0 = blockIdx.y * 128, n0 = blockIdx.x * 128;

    f32x4 acc[4][4];
    #pragma unroll
    for (int i = 0; i < 4; i++)
        #pragma unroll
        for (int j = 0; j < 4; j++) acc[i][j] = (f32x4)(0.f);

    for (int kt = 0; kt < D_DIM; kt += 64) {
        #pragma unroll
        for (int p = 0; p < 4; p++) {
            int j = tid + p * 256;
            int r = j >> 3, c = (j & 7) * 8;
            gload_lds16(XB + (size_t)(m0 + r) * D_DIM + kt + c, &As[r][c]);
            gload_lds16(WdB + (size_t)(n0 + r) * D_DIM + kt + c, &Bs[r][c]);
        }
        __syncthreads();
        #pragma unroll
        for (int kk = 0; kk < 2; kk++) {
            short8 a[4], b[4];
            #pragma unroll
            for (int i = 0; i < 4; i++)
                a[i] = *(const short8*)&As[wm * 64 + i * 16 + cid][kk * 32 + quad * 8];
            #pragma unroll
            for (int j = 0; j < 4; j++)
                b[j] = *(const short8*)&Bs[wn * 64 + j * 16 + cid][kk * 32 + quad * 8];
            #pragma unroll
            for (int i = 0; i < 4; i++)
                #pragma unroll
                for (int j = 0; j < 4; j++)
                    acc[i][j] = __builtin_amdgcn_mfma_f32_16x16x32_bf16(
                        a[i], b[j], acc[i][j], 0, 0, 0);
        }
        __syncthreads();
    }
    #pragma unroll
    for (int j = 0; j < 4; j++) {
        int col = n0 + wn * 64 + j * 16 + cid;
        float bdv = bd[col];
        #pragma unroll
        for (int i = 0; i < 4; i++)
            #pragma unroll
            for (int r = 0; r < 4; r++) {
                int row = m0 + wm * 64 + i * 16 + quad * 4 + r;
                H1[(size_t)row * A_DIM + col] = f2bs(gelu_exact(acc[i][j][r] + bdv));
            }
    }
}

// ---------------------------------------------------------------------------
// expert: H2[m,o] = (valid ? H1[m,:]*eW[idc][o,:] + eb[idc,o] : H1[m,o]) + emb[idc,o]
// M-tile of 128 rows stays inside one sample (S=1024). M=32768,N=256,K=256.
// ---------------------------------------------------------------------------
__global__ __launch_bounds__(256, 2) void k_expert(
    const short* __restrict__ H1, const short* __restrict__ eWB,
    const float* __restrict__ eb, const float* __restrict__ emb,
    const int* __restrict__ domain_id, short* __restrict__ H2)
{
    __shared__ short As[128][64];
    __shared__ short Bs[128][64];
    const int tid  = threadIdx.x;
    const int lane = tid & 63;
    const int w    = tid >> 6;
    const int wm   = w & 1, wn = w >> 1;
    const int quad = lane >> 4, cid = lane & 15;
    const int m0 = blockIdx.y * 128, n0 = blockIdx.x * 128;

    const int samp = m0 >> 10;
    const int id = domain_id[samp];
    const bool valid = (id >= 0) && (id < E_NUM);
    const int idc = id < 0 ? 0 : (id > E_NUM - 1 ? E_NUM - 1 : id);
    const short* Bsrc = eWB + (size_t)idc * A_DIM * A_DIM;

    f32x4 acc[4][4];
    #pragma unroll
    for (int i = 0; i < 4; i++)
        #pragma unroll
        for (int j = 0; j < 4; j++) acc[i][j] = (f32x4)(0.f);

    for (int kt = 0; kt < A_DIM; kt += 64) {
        #pragma unroll
        for (int p = 0; p < 4; p++) {
            int j = tid + p * 256;
            int r = j >> 3, c = (j & 7) * 8;
            gload_lds16(H1 + (size_t)(m0 + r) * A_DIM + kt + c, &As[r][c]);
            gload_lds16(Bsrc + (size_t)(n0 + r) * A_DIM + kt + c, &Bs[r][c]);
        }
        __syncthreads();
        #pragma unroll
        for (int kk = 0; kk < 2; kk++) {
            short8 a[4], b[4];
            #pragma unroll
            for (int i = 0; i < 4; i++)
                a[i] = *(const short8*)&As[wm * 64 + i * 16 + cid][kk * 32 + quad * 8];
            #pragma unroll
            for (int j = 0; j < 4; j++)
                b[j] = *(const short8*)&Bs[wn * 64 + j * 16 + cid][kk * 32 + quad * 8];
            #pragma unroll
            for (int i = 0; i < 4; i++)
                #pragma unroll
                for (int j = 0; j < 4; j++)
                    acc[i][j] = __builtin_amdgcn_mfma_f32_16x16x32_bf16(
                        a[i], b[j], acc[i][j], 0, 0, 0);
        }
        __syncthreads();
    }
    #pragma unroll
    for (int j = 0; j < 4; j++) {
        int col = n0 + wn * 64 + j * 16 + cid;
        float ebv = eb[idc * A_DIM + col];
        float ev  = emb[idc * A_DIM + col];
        #pragma unroll
        for (int i = 0; i < 4; i++)
            #pragma unroll
            for (int r = 0; r < 4; r++) {
                int row = m0 + wm * 64 + i * 16 + quad * 4 + r;
                float base;
                if (valid) base = acc[i][j][r] + ebv;
                else       base = bs2f(H1[(size_t)row * A_DIM + col]);
                H2[(size_t)row * A_DIM + col] = f2bs(base + ev);
            }
    }
}

// ---------------------------------------------------------------------------
// up proj + bias + residual + LayerNorm, fused.
// Block = 32 rows x 1024 cols, 1024 threads / 16 waves; wave owns 64 cols
// -> acc only 32 VGPRs, target 4 waves/EU (16 waves/CU) to hide L2 latency
// of the register-direct B loads. LN rows complete in-block.
// ---------------------------------------------------------------------------
__global__ __launch_bounds__(1024, 4) void k_up_ln(
    const short* __restrict__ H2, const short* __restrict__ WuB,
    const float* __restrict__ ub, const float* __restrict__ X,
    const float* __restrict__ gamma, const float* __restrict__ beta,
    float* __restrict__ out)
{
    __shared__ short As[32][64];
    __shared__ float redS[16][32], red2[16][32];
    __shared__ float muS[32], rsS[32];
    const int tid  = threadIdx.x;
    const int lane = tid & 63;
    const int w    = tid >> 6;            // 0..15
    const int quad = lane >> 4, cid = lane & 15;
    const int m0 = blockIdx.x * 32;
    const int nb = w * 64;                // wave's 64-col slice

    f32x4 acc[2][4];
    #pragma unroll
    for (int mf = 0; mf < 2; mf++)
        #pragma unroll
        for (int j = 0; j < 4; j++) acc[mf][j] = (f32x4)(0.f);

    const short* bbase = WuB + (size_t)(nb + cid) * A_DIM + quad * 8;

    for (int kt = 0; kt < A_DIM; kt += 64) {
        if (tid < 256) {                  // 32x64 bf16 = 4KB: waves 0-3 stage
            int r = tid >> 3, c = (tid & 7) * 8;
            gload_lds16(H2 + (size_t)(m0 + r) * A_DIM + kt + c, &As[r][c]);
        }
        __syncthreads();
        #pragma unroll
        for (int kk = 0; kk < 2; kk++) {
            short8 a0 = *(const short8*)&As[cid][kk * 32 + quad * 8];
            short8 a1 = *(const short8*)&As[16 + cid][kk * 32 + quad * 8];
            #pragma unroll
            for (int j = 0; j < 4; j++) {
                short8 b = *(const short8*)(bbase + (size_t)(j * 16) * A_DIM + kt + kk * 32);
                acc[0][j] = __builtin_amdgcn_mfma_f32_16x16x32_bf16(a0, b, acc[0][j], 0, 0, 0);
                acc[1][j] = __builtin_amdgcn_mfma_f32_16x16x32_bf16(a1, b, acc[1][j], 0, 0, 0);
            }
        }
        __syncthreads();
    }

    // x = acc + up_b + residual; per-row partial sums
    float s1[2][4], s2[2][4];
    #pragma unroll
    for (int mf = 0; mf < 2; mf++)
        #pragma unroll
        for (int r = 0; r < 4; r++) { s1[mf][r] = 0.f; s2[mf][r] = 0.f; }
    #pragma unroll
    for (int j = 0; j < 4; j++) {
        int col = nb + j * 16 + cid;
        float ubv = ub[col];
        #pragma unroll
        for (int mf = 0; mf < 2; mf++)
            #pragma unroll
            for (int r = 0; r < 4; r++) {
                int row = m0 + mf * 16 + quad * 4 + r;
                float x = acc[mf][j][r] + ubv + X[(size_t)row * D_DIM + col];
                acc[mf][j][r] = x;
                s1[mf][r] += x;
                s2[mf][r] += x * x;
            }
    }
    // reduce across the 16 lanes (cid) sharing a row
    #pragma unroll
    for (int mf = 0; mf < 2; mf++)
        #pragma unroll
        for (int r = 0; r < 4; r++) {
            float a = s1[mf][r], b = s2[mf][r];
            #pragma unroll
            for (int off = 1; off < 16; off <<= 1) {
                a += __shfl_xor(a, off, 64);
                b += __shfl_xor(b, off, 64);
            }
            if (cid == 0) {
                int rl = mf * 16 + quad * 4 + r;
                redS[w][rl] = a;
                red2[w][rl] = b;
            }
        }
    __syncthreads();
    if (tid < 32) {
        float S = 0.f, Q = 0.f;
        #pragma unroll
        for (int ww = 0; ww < 16; ww++) { S += redS[ww][tid]; Q += red2[ww][tid]; }
        float mu = S * (1.0f / 1024.0f);
        float var = Q * (1.0f / 1024.0f) - mu * mu;
        muS[tid] = mu;
        rsS[tid] = rsqrtf(var + 1e-5f);
    }
    __syncthreads();
    #pragma unroll
    for (int j = 0; j < 4; j++) {
        int col = nb + j * 16 + cid;
        float g = gamma[col], be = beta[col];
        #pragma unroll
        for (int mf = 0; mf < 2; mf++)
            #pragma unroll
            for (int r = 0; r < 4; r++) {
                int rl = mf * 16 + quad * 4 + r;
                out[(size_t)(m0 + rl) * D_DIM + col] =
                    (acc[mf][j][r] - muS[rl]) * rsS[rl] * g + be;
            }
    }
}

extern "C" void kernel_launch(void* const* d_in, const int* in_sizes, int n_in,
                              void* d_out, int out_size, void* d_ws, size_t ws_size,
                              hipStream_t stream) {
    const float* hs  = (const float*)d_in[0];   // [32,1024,1024]
    const int*   did = (const int*)d_in[1];     // [32]
    const float* dW  = (const float*)d_in[2];   // [256,1024]
    const float* db  = (const float*)d_in[3];   // [256]
    const float* uW  = (const float*)d_in[4];   // [1024,256]
    const float* ub  = (const float*)d_in[5];   // [1024]
    const float* eW  = (const float*)d_in[6];   // [16,256,256]
    const float* ebv = (const float*)d_in[7];   // [16,256]
    const float* emb = (const float*)d_in[8];   // [16,256]
    const float* gam = (const float*)d_in[9];   // [1024]
    const float* bet = (const float*)d_in[10];  // [1024]
    float* out = (float*)d_out;

    char* ws = (char*)d_ws;
    short* XB  = (short*)(ws);                            // 64 MB
    short* WdB = (short*)(ws + (64u << 20));              // 512 KB
    short* WuB = (short*)(ws + (64u << 20) + (1u << 19)); // 512 KB
    short* eWB = (short*)(ws + (65u << 20));              // 2 MB
    short* H1  = (short*)(ws + (68u << 20));              // 16 MB
    short* H2  = (short*)(ws + (84u << 20));              // 16 MB (total 100 MB)

    k_cast  <<<16384, 256, 0, stream>>>(hs, dW, uW, eW, XB, WdB, WuB, eWB);
    k_down  <<<dim3(2, 256), 256, 0, stream>>>(XB, WdB, db, H1);
    k_expert<<<dim3(2, 256), 256, 0, stream>>>(H1, eWB, ebv, emb, did, H2);
    k_up_ln <<<1024, 1024, 0, stream>>>(H2, WuB, ub, hs, gam, bet, out);
}